// Round 2
// 94.356 us; speedup vs baseline: 1.0130x; 1.0130x over previous
//
#include <hip/hip_runtime.h>

#define CONVEX_WEIGHT 0.1f

// Branchless compare-exchange on (ax,ay),(bx,by) by angle = atan2(y,x) in (-pi,pi].
// atan2 < 0 <=> y < 0. Same half-plane: span < pi, so cross(a,b)>0 <=> ang(a)<ang(b).
// All selects -> v_cndmask, no control flow, no address-taken arrays (SROA-safe).
#define ANG_CE(ax, ay, bx, by)                                            \
    {                                                                     \
        bool ha = (ay) < 0.0f;                                            \
        bool hb = (by) < 0.0f;                                            \
        float cr_ = (ax) * (by) - (ay) * (bx);                            \
        bool a_first = (ha == hb) ? (cr_ > 0.0f) : ha;                    \
        float t;                                                          \
        t = a_first ? (ax) : (bx); (bx) = a_first ? (bx) : (ax); (ax) = t;\
        t = a_first ? (ay) : (by); (by) = a_first ? (by) : (ay); (ay) = t;\
    }

__global__ __launch_bounds__(256) void mgiou2dplus_kernel(
    const float4* __restrict__ pred4,
    const float4* __restrict__ targ4,
    float* __restrict__ out,
    int B)
{
    int b = blockIdx.x * blockDim.x + threadIdx.x;
    if (b >= B) return;

    // ---- plain cached loads: inputs were just d2d-restored, so they sit in
    // L3 (256 MB >> 64 MB of inputs); nt hints would forfeit those hits ----
    float4 pa = pred4[2 * b];
    float4 pb = pred4[2 * b + 1];
    float4 ta = targ4[2 * b];
    float4 tb = targ4[2 * b + 1];

    float px0 = pa.x, py0 = pa.y, px1 = pa.z, py1 = pa.w;
    float px2 = pb.x, py2 = pb.y, px3 = pb.z, py3 = pb.w;
    float tx0 = ta.x, ty0 = ta.y, tx1 = ta.z, ty1 = ta.w;
    float tx2 = tb.x, ty2 = tb.y, tx3 = tb.z, ty3 = tb.w;

    // ---- centers, centered coords ----
    float pcx = (px0 + px1 + px2 + px3) * 0.25f;
    float pcy = (py0 + py1 + py2 + py3) * 0.25f;
    float tcx = (tx0 + tx1 + tx2 + tx3) * 0.25f;
    float tcy = (ty0 + ty1 + ty2 + ty3) * 0.25f;

    float a0x = px0 - pcx, a0y = py0 - pcy;
    float a1x = px1 - pcx, a1y = py1 - pcy;
    float a2x = px2 - pcx, a2y = py2 - pcy;
    float a3x = px3 - pcx, a3y = py3 - pcy;

    float b0x = tx0 - tcx, b0y = ty0 - tcy;
    float b1x = tx1 - tcx, b1y = ty1 - tcy;
    float b2x = tx2 - tcx, b2y = ty2 - tcy;
    float b3x = tx3 - tcx, b3y = ty3 - tcy;

    // ---- 5-CE sorting network, ascending by angle (branchless) ----
    ANG_CE(a0x, a0y, a1x, a1y) ANG_CE(a2x, a2y, a3x, a3y)
    ANG_CE(a0x, a0y, a2x, a2y) ANG_CE(a1x, a1y, a3x, a3y)
    ANG_CE(a1x, a1y, a2x, a2y)

    ANG_CE(b0x, b0y, b1x, b1y) ANG_CE(b2x, b2y, b3x, b3y)
    ANG_CE(b0x, b0y, b2x, b2y) ANG_CE(b1x, b1y, b3x, b3y)
    ANG_CE(b1x, b1y, b2x, b2y)

    // ---- sorted ORIGINAL-frame coords (sorted centered + center) ----
    // Needed so the own-polygon projections live in the same frame as the
    // other polygon's original coords (intervals must share an origin).
    float s0x = a0x + pcx, s0y = a0y + pcy;
    float s1x = a1x + pcx, s1y = a1y + pcy;
    float s2x = a2x + pcx, s2y = a2y + pcy;
    float s3x = a3x + pcx, s3y = a3y + pcy;

    float u0x = b0x + tcx, u0y = b0y + tcy;
    float u1x = b1x + tcx, u1y = b1y + tcy;
    float u2x = b2x + tcx, u2y = b2y + tcy;
    float u3x = b3x + tcx, u3y = b3y + tcy;

    // ---- per-axis 1D GIoU; axis = normal(edge) = (ey, -ex) ----
    // Own-edge identity: the axis normal is perpendicular to its source edge,
    // so BOTH edge endpoints project to the same value -> own side needs only
    // 3 dots (qe counted once) and a 3-way min/max. Cross side projects the
    // other polygon's original (unsorted) verts, same frame. Per-axis giou is
    // kept as a fraction (num, den); fractions combine pairwise so the whole
    // 8-axis sum costs ONE reciprocal instead of eight.
    //   num = inter*hull - (hull-uni)*uni = hull*(inter-uni) + uni^2 (1 fma)
    float num[8], den[8];
    int axi = 0;

#define AXIS_GIOU(nx, ny, ex, ey, cx, cy, dx, dy,                          \
                  X0, Y0, X1, Y1, X2, Y2, X3, Y3)                          \
    {                                                                      \
        float nx_ = (nx), ny_ = (ny);                                      \
        float qe = (ex) * nx_ + (ey) * ny_;                                \
        float qc = (cx) * nx_ + (cy) * ny_;                                \
        float qd = (dx) * nx_ + (dy) * ny_;                                \
        float mn1 = fminf(qe, fminf(qc, qd));                              \
        float mx1 = fmaxf(qe, fmaxf(qc, qd));                              \
        float r0 = (X0) * nx_ + (Y0) * ny_;                                \
        float r1 = (X1) * nx_ + (Y1) * ny_;                                \
        float r2 = (X2) * nx_ + (Y2) * ny_;                                \
        float r3 = (X3) * nx_ + (Y3) * ny_;                                \
        float mn2 = fminf(fminf(r0, r1), fminf(r2, r3));                   \
        float mx2 = fmaxf(fmaxf(r0, r1), fmaxf(r2, r3));                   \
        float inter = fmaxf(fminf(mx1, mx2) - fmaxf(mn1, mn2), 0.0f);      \
        float uni   = (mx1 - mn1) + (mx2 - mn2) - inter;                   \
        float hull  = fmaxf(mx1, mx2) - fminf(mn1, mn2);                   \
        num[axi] = hull * (inter - uni) + uni * uni;                       \
        den[axi] = uni * hull;                                             \
        ++axi;                                                             \
    }

    // pred axes: edge k -> k+1 of sorted pred; equal-endpoint = s_k,
    // remaining own verts = s_{k+2}, s_{k+3}; cross side = original target.
    AXIS_GIOU(a1y - a0y, a0x - a1x, s0x, s0y, s2x, s2y, s3x, s3y,
              tx0, ty0, tx1, ty1, tx2, ty2, tx3, ty3)
    AXIS_GIOU(a2y - a1y, a1x - a2x, s1x, s1y, s3x, s3y, s0x, s0y,
              tx0, ty0, tx1, ty1, tx2, ty2, tx3, ty3)
    AXIS_GIOU(a3y - a2y, a2x - a3x, s2x, s2y, s0x, s0y, s1x, s1y,
              tx0, ty0, tx1, ty1, tx2, ty2, tx3, ty3)
    AXIS_GIOU(a0y - a3y, a3x - a0x, s3x, s3y, s1x, s1y, s2x, s2y,
              tx0, ty0, tx1, ty1, tx2, ty2, tx3, ty3)
    // target axes: own side = sorted target originals, cross = original pred.
    AXIS_GIOU(b1y - b0y, b0x - b1x, u0x, u0y, u2x, u2y, u3x, u3y,
              px0, py0, px1, py1, px2, py2, px3, py3)
    AXIS_GIOU(b2y - b1y, b1x - b2x, u1x, u1y, u3x, u3y, u0x, u0y,
              px0, py0, px1, py1, px2, py2, px3, py3)
    AXIS_GIOU(b3y - b2y, b2x - b3x, u2x, u2y, u0x, u0y, u1x, u1y,
              px0, py0, px1, py1, px2, py2, px3, py3)
    AXIS_GIOU(b0y - b3y, b3x - b0x, u3x, u3y, u1x, u1y, u2x, u2y,
              px0, py0, px1, py1, px2, py2, px3, py3)
#undef AXIS_GIOU

    // Pairwise fraction combine: 7 combines, then a single fast divide.
    float n01 = num[0] * den[1] + num[1] * den[0], d01 = den[0] * den[1];
    float n23 = num[2] * den[3] + num[3] * den[2], d23 = den[2] * den[3];
    float n45 = num[4] * den[5] + num[5] * den[4], d45 = den[4] * den[5];
    float n67 = num[6] * den[7] + num[7] * den[6], d67 = den[6] * den[7];
    float n03 = n01 * d23 + n23 * d01, d03 = d01 * d23;
    float n47 = n45 * d67 + n67 * d45, d47 = d45 * d67;
    float nall = n03 * d47 + n47 * d03, dall = d03 * d47;
    float gsum = __fdividef(nall, dall);

    float loss = (1.0f - gsum * 0.125f) * 0.5f;

    // ---- convexity penalty on pred (original vertex order) ----
    float c0, c1, c2, c3;
    {
        float e1x, e1y, e2x, e2y;
        e1x = px3 - px0; e1y = py3 - py0; e2x = px1 - px0; e2y = py1 - py0;
        c0 = e1x * e2y - e1y * e2x;
        e1x = px0 - px1; e1y = py0 - py1; e2x = px2 - px1; e2y = py2 - py1;
        c1 = e1x * e2y - e1y * e2x;
        e1x = px1 - px2; e1y = py1 - py2; e2x = px3 - px2; e2y = py3 - py2;
        c2 = e1x * e2y - e1y * e2x;
        e1x = px2 - px3; e1y = py2 - py3; e2x = px0 - px3; e2y = py0 - py3;
        c3 = e1x * e2y - e1y * e2x;
    }
    float sref = (c0 < 0.0f) ? -1.0f : 1.0f;   // sign(c0), 0 -> +1
    float pen = fmaxf(-sref * c0, 0.0f) + fmaxf(-sref * c1, 0.0f)
              + fmaxf(-sref * c2, 0.0f) + fmaxf(-sref * c3, 0.0f);

    loss += CONVEX_WEIGHT * (pen * 0.25f);

    // nt store is safe: d_out is only read back host-side after the replay.
    __builtin_nontemporal_store(loss, &out[b]);
}

extern "C" void kernel_launch(void* const* d_in, const int* in_sizes, int n_in,
                              void* d_out, int out_size, void* d_ws, size_t ws_size,
                              hipStream_t stream)
{
    const float4* pred = (const float4*)d_in[0];
    const float4* targ = (const float4*)d_in[1];
    float* out = (float*)d_out;
    int B = in_sizes[0] / 8;   // (B, 4, 2) floats

    const int threads = 256;
    int blocks = (B + threads - 1) / threads;
    mgiou2dplus_kernel<<<blocks, threads, 0, stream>>>(pred, targ, out, B);
}